// Round 1
// baseline (3848.347 us; speedup 1.0000x reference)
//
#include <hip/hip_runtime.h>
#include <cstddef>

#define NN 50000
#define NE 800000
#define BN_EPS 1e-5f

// ---------------- degree kernels ----------------
__global__ __launch_bounds__(256) void k_init_deg(float* __restrict__ deg) {
    int i = blockIdx.x * 256 + threadIdx.x;
    if (i < NN) deg[i] = 1.0f;
}

__global__ __launch_bounds__(256) void k_count(const int* __restrict__ dst, float* __restrict__ deg) {
    int e = blockIdx.x * 256 + threadIdx.x;
    if (e < NE) atomicAdd(&deg[dst[e]], 1.0f);
}

__global__ __launch_bounds__(256) void k_deg_fin(const float* __restrict__ deg,
                                                 float* __restrict__ dsq,
                                                 float* __restrict__ dinv) {
    int i = blockIdx.x * 256 + threadIdx.x;
    if (i < NN) {
        float d = deg[i];
        dsq[i] = rsqrtf(d);
        dinv[i] = 1.0f / d;
    }
}

// ---------------- fp32 tiled GEMM: C[M,N] = A[M,K] @ B[K,N] ----------------
// 64x64 tile, 256 threads, 4x4 micro-tile, BK=16. K % 16 == 0, N % 64 == 0.
__global__ __launch_bounds__(256) void k_gemm(const float* __restrict__ A,
                                              const float* __restrict__ B,
                                              float* __restrict__ C,
                                              int M, int K, int N) {
    __shared__ float As[16][68];
    __shared__ float Bs[16][68];
    const int tid = threadIdx.x;
    const int tx = tid & 15, ty = tid >> 4;
    const int row0 = blockIdx.y * 64, col0 = blockIdx.x * 64;
    float acc[4][4] = {};

    for (int kk = 0; kk < K; kk += 16) {
        #pragma unroll
        for (int i = 0; i < 4; ++i) {
            int idx = tid + i * 256;
            int m = idx >> 4, k = idx & 15;
            int gr = row0 + m;
            As[k][m] = (gr < M) ? A[(size_t)gr * K + kk + k] : 0.0f;
        }
        #pragma unroll
        for (int i = 0; i < 4; ++i) {
            int idx = tid + i * 256;
            int k = idx >> 6, n = idx & 63;
            Bs[k][n] = B[(size_t)(kk + k) * N + col0 + n];
        }
        __syncthreads();
        #pragma unroll
        for (int k = 0; k < 16; ++k) {
            float4 a4 = *reinterpret_cast<const float4*>(&As[k][ty * 4]);
            float4 b4 = *reinterpret_cast<const float4*>(&Bs[k][tx * 4]);
            float av[4] = {a4.x, a4.y, a4.z, a4.w};
            float bv[4] = {b4.x, b4.y, b4.z, b4.w};
            #pragma unroll
            for (int i = 0; i < 4; ++i)
                #pragma unroll
                for (int j = 0; j < 4; ++j)
                    acc[i][j] = fmaf(av[i], bv[j], acc[i][j]);
        }
        __syncthreads();
    }
    #pragma unroll
    for (int i = 0; i < 4; ++i) {
        int gr = row0 + ty * 4 + i;
        if (gr < M) {
            float4 v = make_float4(acc[i][0], acc[i][1], acc[i][2], acc[i][3]);
            *reinterpret_cast<float4*>(&C[(size_t)gr * N + col0 + tx * 4]) = v;
        }
    }
}

// ---------------- scatter-add: agg[dst] += h[src] * dsq[src]*dsq[dst] ----------------
// one wave (64 lanes) per edge
template <int D>
__global__ __launch_bounds__(256) void k_scatter(const float* __restrict__ h,
                                                 const int* __restrict__ src,
                                                 const int* __restrict__ dst,
                                                 const float* __restrict__ dsq,
                                                 float* __restrict__ agg) {
    int e = blockIdx.x * 4 + (threadIdx.x >> 6);
    if (e >= NE) return;
    int lane = threadIdx.x & 63;
    int s = src[e], d = dst[e];
    float norm = dsq[s] * dsq[d];
    if (D == 256) {
        float4 v = *reinterpret_cast<const float4*>(h + (size_t)s * 256 + lane * 4);
        float* p = agg + (size_t)d * 256 + lane * 4;
        atomicAdd(p + 0, v.x * norm);
        atomicAdd(p + 1, v.y * norm);
        atomicAdd(p + 2, v.z * norm);
        atomicAdd(p + 3, v.w * norm);
    } else {
        atomicAdd(agg + (size_t)d * 64 + lane, h[(size_t)s * 64 + lane] * norm);
    }
}

// ---------------- out += h * dinv[n] + b[c]; optional relu ----------------
template <int D, bool RELU>
__global__ __launch_bounds__(256) void k_self_bias(float* __restrict__ out,
                                                   const float* __restrict__ h,
                                                   const float* __restrict__ dinv,
                                                   const float* __restrict__ b) {
    int i = blockIdx.x * 256 + threadIdx.x;
    if (i >= NN * D) return;
    int n = i / D, c = i & (D - 1);
    float v = out[i] + h[i] * dinv[n] + b[c];
    if (RELU) v = fmaxf(v, 0.0f);
    out[i] = v;
}

// ---------------- BatchNorm ----------------
template <int C>
__global__ __launch_bounds__(256) void k_bn_stats(const float* __restrict__ x,
                                                  float* __restrict__ stats) {
    int c = threadIdx.x & (C - 1);
    int rstart = blockIdx.x * (256 / C) + (threadIdx.x / C);
    int rstride = gridDim.x * (256 / C);
    float s = 0.0f, ss = 0.0f;
    for (int r = rstart; r < NN; r += rstride) {
        float v = x[(size_t)r * C + c];
        s += v;
        ss += v * v;
    }
    atomicAdd(&stats[c], s);
    atomicAdd(&stats[C + c], ss);
}

__global__ __launch_bounds__(256) void k_bn_fin(float* __restrict__ stats, int C) {
    int c = threadIdx.x;
    if (c < C) {
        const float invN = 1.0f / (float)NN;
        float mean = stats[c] * invN;
        float var = stats[C + c] * invN - mean * mean;
        stats[c] = mean;
        stats[C + c] = rsqrtf(var + BN_EPS);
    }
}

template <int C>
__global__ __launch_bounds__(256) void k_bn_apply(float* __restrict__ x,
                                                  const float* __restrict__ stats,
                                                  const float* __restrict__ g,
                                                  const float* __restrict__ be) {
    int i = blockIdx.x * 256 + threadIdx.x;
    if (i >= NN * C) return;
    int c = i & (C - 1);
    float v = (x[i] - stats[c]) * stats[C + c] * g[c] + be[c];
    x[i] = fmaxf(v, 0.0f);
}

// ---------------- edge MLP: one edge per lane ----------------
__global__ __launch_bounds__(256) void k_edge_mlp(const float* __restrict__ emb,
                                                  const int* __restrict__ src,
                                                  const int* __restrict__ dst,
                                                  const float* __restrict__ W1,
                                                  const float* __restrict__ b1,
                                                  const float* __restrict__ W2,
                                                  const float* __restrict__ b2,
                                                  const float* __restrict__ W3,
                                                  const float* __restrict__ b3,
                                                  float* __restrict__ out) {
    int e = blockIdx.x * 256 + threadIdx.x;
    if (e >= NE) return;
    int s = src[e], d = dst[e];
    const float4* es4 = reinterpret_cast<const float4*>(emb + (size_t)s * 64);
    const float4* ed4 = reinterpret_cast<const float4*>(emb + (size_t)d * 64);

    float h1[64];
    #pragma unroll
    for (int j = 0; j < 64; ++j) h1[j] = b1[j];

    for (int k4 = 0; k4 < 16; ++k4) {
        float4 ev = es4[k4];
        float evv[4] = {ev.x, ev.y, ev.z, ev.w};
        #pragma unroll
        for (int kk = 0; kk < 4; ++kk) {
            float ek = evv[kk];
            const float* wr = W1 + (size_t)(k4 * 4 + kk) * 64;
            #pragma unroll
            for (int j = 0; j < 64; ++j) h1[j] = fmaf(ek, wr[j], h1[j]);
        }
    }
    for (int k4 = 0; k4 < 16; ++k4) {
        float4 ev = ed4[k4];
        float evv[4] = {ev.x, ev.y, ev.z, ev.w};
        #pragma unroll
        for (int kk = 0; kk < 4; ++kk) {
            float ek = evv[kk];
            const float* wr = W1 + (size_t)(64 + k4 * 4 + kk) * 64;
            #pragma unroll
            for (int j = 0; j < 64; ++j) h1[j] = fmaf(ek, wr[j], h1[j]);
        }
    }

    float h2[32];
    #pragma unroll
    for (int j = 0; j < 32; ++j) h2[j] = b2[j];
    for (int k = 0; k < 64; ++k) {
        float hk = fmaxf(h1[k], 0.0f);
        const float* wr = W2 + (size_t)k * 32;
        #pragma unroll
        for (int j = 0; j < 32; ++j) h2[j] = fmaf(hk, wr[j], h2[j]);
    }

    float o0 = b3[0], o1 = b3[1];
    #pragma unroll
    for (int k = 0; k < 32; ++k) {
        float hk = fmaxf(h2[k], 0.0f);
        o0 = fmaf(hk, W3[2 * k + 0], o0);
        o1 = fmaf(hk, W3[2 * k + 1], o1);
    }
    float2 o = make_float2(o0, o1);
    *reinterpret_cast<float2*>(out + (size_t)2 * e) = o;
}

// ---------------- launch ----------------
extern "C" void kernel_launch(void* const* d_in, const int* in_sizes, int n_in,
                              void* d_out, int out_size, void* d_ws, size_t ws_size,
                              hipStream_t stream) {
    const float* x    = (const float*)d_in[0];
    const int*   ei   = (const int*)d_in[1];
    const int*   src  = ei;
    const int*   dst  = ei + NE;
    const float* W1   = (const float*)d_in[2];
    const float* b1   = (const float*)d_in[3];
    const float* g1   = (const float*)d_in[4];
    const float* be1  = (const float*)d_in[5];
    const float* W2   = (const float*)d_in[6];
    const float* b2   = (const float*)d_in[7];
    const float* g2   = (const float*)d_in[8];
    const float* be2  = (const float*)d_in[9];
    const float* W3   = (const float*)d_in[10];
    const float* b3   = (const float*)d_in[11];
    const float* We1  = (const float*)d_in[12];
    const float* bme1 = (const float*)d_in[13];
    const float* We2  = (const float*)d_in[14];
    const float* bme2 = (const float*)d_in[15];
    const float* We3  = (const float*)d_in[16];
    const float* bme3 = (const float*)d_in[17];
    float* out = (float*)d_out;
    float* ws  = (float*)d_ws;

    const int NPAD = 50176;
    float* deg   = ws;
    float* dsq   = ws + NPAD;
    float* dinv  = ws + 2 * NPAD;
    float* stats = ws + 3 * NPAD;            // 1024 floats reserved
    float* bufH  = ws + 3 * NPAD + 1024;     // N*256
    float* bufO  = bufH + (size_t)NN * 256;  // N*256

    const int nblkN = (NN + 255) / 256;
    const int nblkE = (NE + 255) / 256;
    const int nblkEdgeWave = (NE + 3) / 4;  // 1 wave per edge, 4 waves/block

    // degrees
    k_init_deg<<<nblkN, 256, 0, stream>>>(deg);
    k_count<<<nblkE, 256, 0, stream>>>(dst, deg);
    k_deg_fin<<<nblkN, 256, 0, stream>>>(deg, dsq, dinv);

    // ---- layer 1: 256 -> 256, BN, relu ----
    {
        dim3 g(4, (NN + 63) / 64);
        k_gemm<<<g, 256, 0, stream>>>(x, W1, bufH, NN, 256, 256);
    }
    hipMemsetAsync(bufO, 0, (size_t)NN * 256 * sizeof(float), stream);
    k_scatter<256><<<nblkEdgeWave, 256, 0, stream>>>(bufH, src, dst, dsq, bufO);
    k_self_bias<256, false><<<(NN * 256) / 256, 256, 0, stream>>>(bufO, bufH, dinv, b1);
    hipMemsetAsync(stats, 0, 1024 * sizeof(float), stream);
    k_bn_stats<256><<<256, 256, 0, stream>>>(bufO, stats);
    k_bn_fin<<<1, 256, 0, stream>>>(stats, 256);
    k_bn_apply<256><<<(NN * 256) / 256, 256, 0, stream>>>(bufO, stats, g1, be1);

    // ---- layer 2: 256 -> 64, BN, relu ----
    {
        dim3 g(1, (NN + 63) / 64);
        k_gemm<<<g, 256, 0, stream>>>(bufO, W2, bufH, NN, 256, 64);
    }
    hipMemsetAsync(bufO, 0, (size_t)NN * 64 * sizeof(float), stream);
    k_scatter<64><<<nblkEdgeWave, 256, 0, stream>>>(bufH, src, dst, dsq, bufO);
    k_self_bias<64, false><<<(NN * 64) / 256, 256, 0, stream>>>(bufO, bufH, dinv, b2);
    hipMemsetAsync(stats, 0, 1024 * sizeof(float), stream);
    k_bn_stats<64><<<256, 256, 0, stream>>>(bufO, stats);
    k_bn_fin<<<1, 256, 0, stream>>>(stats, 64);
    k_bn_apply<64><<<(NN * 64) / 256, 256, 0, stream>>>(bufO, stats, g2, be2);

    // ---- layer 3: 64 -> 64, relu ----
    {
        dim3 g(1, (NN + 63) / 64);
        k_gemm<<<g, 256, 0, stream>>>(bufO, W3, bufH, NN, 64, 64);
    }
    hipMemsetAsync(bufO, 0, (size_t)NN * 64 * sizeof(float), stream);
    k_scatter<64><<<nblkEdgeWave, 256, 0, stream>>>(bufH, src, dst, dsq, bufO);
    k_self_bias<64, true><<<(NN * 64) / 256, 256, 0, stream>>>(bufO, bufH, dinv, b3);

    // ---- layer 4: 64 -> 64 (same W3/b3, no relu) -> emb ----
    {
        dim3 g(1, (NN + 63) / 64);
        k_gemm<<<g, 256, 0, stream>>>(bufO, W3, bufH, NN, 64, 64);
    }
    hipMemsetAsync(bufO, 0, (size_t)NN * 64 * sizeof(float), stream);
    k_scatter<64><<<nblkEdgeWave, 256, 0, stream>>>(bufH, src, dst, dsq, bufO);
    k_self_bias<64, false><<<(NN * 64) / 256, 256, 0, stream>>>(bufO, bufH, dinv, b3);

    // ---- edge MLP ----
    k_edge_mlp<<<nblkE, 256, 0, stream>>>(bufO, src, dst, We1, bme1, We2, bme2, We3, bme3, out);

    (void)in_sizes; (void)n_in; (void)out_size; (void)ws_size;
}

// Round 2
// 1163.661 us; speedup vs baseline: 3.3071x; 3.3071x over previous
//
#include <hip/hip_runtime.h>
#include <cstddef>

#define NN 50000
#define NE 800000
#define NPAD 50176
#define BN_EPS 1e-5f

// ---------------- CSR build ----------------
__global__ __launch_bounds__(256) void k_count_int(const int* __restrict__ dst,
                                                   int* __restrict__ cnt) {
    int e = blockIdx.x * 256 + threadIdx.x;
    if (e < NE) atomicAdd(&cnt[dst[e]], 1);
}

// single block, 1024 threads: exclusive scan of cnt -> row_start; cnt becomes cursor;
// also computes dsq = rsqrt(deg), dinv = 1/deg with deg = cnt+1 (self loop).
__global__ __launch_bounds__(1024) void k_scan(int* __restrict__ cnt,
                                               int* __restrict__ row_start,
                                               float* __restrict__ dsq,
                                               float* __restrict__ dinv) {
    __shared__ int part[1024];
    const int t = threadIdx.x;
    const int CHUNK = (NN + 1023) / 1024;
    int begin = t * CHUNK, end = min(begin + CHUNK, NN);
    int s = 0;
    for (int i = begin; i < end; ++i) s += cnt[i];
    part[t] = s;
    __syncthreads();
    for (int off = 1; off < 1024; off <<= 1) {
        int v = (t >= off) ? part[t - off] : 0;
        __syncthreads();
        part[t] += v;
        __syncthreads();
    }
    int running = (t == 0) ? 0 : part[t - 1];
    for (int i = begin; i < end; ++i) {
        int c = cnt[i];
        row_start[i] = running;
        cnt[i] = running;  // becomes the fill cursor
        running += c;
        float d = (float)c + 1.0f;
        dsq[i] = rsqrtf(d);
        dinv[i] = 1.0f / d;
    }
    if (t == 0) row_start[NN] = part[1023];
}

__global__ __launch_bounds__(256) void k_fill(const int* __restrict__ src,
                                              const int* __restrict__ dst,
                                              int* __restrict__ cursor,
                                              int* __restrict__ csr_src) {
    int e = blockIdx.x * 256 + threadIdx.x;
    if (e < NE) {
        int pos = atomicAdd(&cursor[dst[e]], 1);
        csr_src[pos] = src[e];
    }
}

// ---------------- fp32 tiled GEMM: C[M,N] = A[M,K] @ B[K,N] ----------------
__global__ __launch_bounds__(256) void k_gemm(const float* __restrict__ A,
                                              const float* __restrict__ B,
                                              float* __restrict__ C,
                                              int M, int K, int N) {
    __shared__ float As[16][68];
    __shared__ float Bs[16][68];
    const int tid = threadIdx.x;
    const int tx = tid & 15, ty = tid >> 4;
    const int row0 = blockIdx.y * 64, col0 = blockIdx.x * 64;
    float acc[4][4] = {};

    for (int kk = 0; kk < K; kk += 16) {
        #pragma unroll
        for (int i = 0; i < 4; ++i) {
            int idx = tid + i * 256;
            int m = idx >> 4, k = idx & 15;
            int gr = row0 + m;
            As[k][m] = (gr < M) ? A[(size_t)gr * K + kk + k] : 0.0f;
        }
        #pragma unroll
        for (int i = 0; i < 4; ++i) {
            int idx = tid + i * 256;
            int k = idx >> 6, n = idx & 63;
            Bs[k][n] = B[(size_t)(kk + k) * N + col0 + n];
        }
        __syncthreads();
        #pragma unroll
        for (int k = 0; k < 16; ++k) {
            float4 a4 = *reinterpret_cast<const float4*>(&As[k][ty * 4]);
            float4 b4 = *reinterpret_cast<const float4*>(&Bs[k][tx * 4]);
            float av[4] = {a4.x, a4.y, a4.z, a4.w};
            float bv[4] = {b4.x, b4.y, b4.z, b4.w};
            #pragma unroll
            for (int i = 0; i < 4; ++i)
                #pragma unroll
                for (int j = 0; j < 4; ++j)
                    acc[i][j] = fmaf(av[i], bv[j], acc[i][j]);
        }
        __syncthreads();
    }
    #pragma unroll
    for (int i = 0; i < 4; ++i) {
        int gr = row0 + ty * 4 + i;
        if (gr < M) {
            float4 v = make_float4(acc[i][0], acc[i][1], acc[i][2], acc[i][3]);
            *reinterpret_cast<float4*>(&C[(size_t)gr * N + col0 + tx * 4]) = v;
        }
    }
}

// ---------------- CSR aggregation, D=256: one wave per node, float4 lanes ----------------
// out[d] = dsq[d]*sum_{s in row} dsq[s]*h[s]  +  h[d]*dinv[d]  +  b
__global__ __launch_bounds__(256) void k_agg256(const float* __restrict__ h,
                                                const int* __restrict__ row_start,
                                                const int* __restrict__ csr_src,
                                                const float* __restrict__ dsq,
                                                const float* __restrict__ dinv,
                                                const float* __restrict__ b,
                                                float* __restrict__ out) {
    int d = blockIdx.x * 4 + (threadIdx.x >> 6);
    if (d >= NN) return;
    int lane = threadIdx.x & 63;
    int rs = row_start[d], re = row_start[d + 1];
    float4 acc = make_float4(0.f, 0.f, 0.f, 0.f);
    for (int j = rs; j < re; ++j) {
        int s = csr_src[j];
        float w = dsq[s];
        float4 v = *reinterpret_cast<const float4*>(h + (size_t)s * 256 + lane * 4);
        acc.x = fmaf(v.x, w, acc.x);
        acc.y = fmaf(v.y, w, acc.y);
        acc.z = fmaf(v.z, w, acc.z);
        acc.w = fmaf(v.w, w, acc.w);
    }
    float sd = dsq[d], di = dinv[d];
    float4 hv = *reinterpret_cast<const float4*>(h + (size_t)d * 256 + lane * 4);
    float4 bv = *reinterpret_cast<const float4*>(b + lane * 4);
    float4 o;
    o.x = fmaf(acc.x, sd, fmaf(hv.x, di, bv.x));
    o.y = fmaf(acc.y, sd, fmaf(hv.y, di, bv.y));
    o.z = fmaf(acc.z, sd, fmaf(hv.z, di, bv.z));
    o.w = fmaf(acc.w, sd, fmaf(hv.w, di, bv.w));
    *reinterpret_cast<float4*>(out + (size_t)d * 256 + lane * 4) = o;
}

// ---------------- CSR aggregation, D=64: one wave per node ----------------
template <bool RELU>
__global__ __launch_bounds__(256) void k_agg64(const float* __restrict__ h,
                                               const int* __restrict__ row_start,
                                               const int* __restrict__ csr_src,
                                               const float* __restrict__ dsq,
                                               const float* __restrict__ dinv,
                                               const float* __restrict__ b,
                                               float* __restrict__ out) {
    int d = blockIdx.x * 4 + (threadIdx.x >> 6);
    if (d >= NN) return;
    int lane = threadIdx.x & 63;
    int rs = row_start[d], re = row_start[d + 1];
    float acc = 0.0f;
    for (int j = rs; j < re; ++j) {
        int s = csr_src[j];
        acc = fmaf(h[(size_t)s * 64 + lane], dsq[s], acc);
    }
    float o = fmaf(acc, dsq[d], fmaf(h[(size_t)d * 64 + lane], dinv[d], b[lane]));
    if (RELU) o = fmaxf(o, 0.0f);
    out[(size_t)d * 64 + lane] = o;
}

// ---------------- BatchNorm ----------------
template <int C>
__global__ __launch_bounds__(256) void k_bn_stats(const float* __restrict__ x,
                                                  float* __restrict__ stats) {
    int c = threadIdx.x & (C - 1);
    int rstart = blockIdx.x * (256 / C) + (threadIdx.x / C);
    int rstride = gridDim.x * (256 / C);
    float s = 0.0f, ss = 0.0f;
    for (int r = rstart; r < NN; r += rstride) {
        float v = x[(size_t)r * C + c];
        s += v;
        ss += v * v;
    }
    atomicAdd(&stats[c], s);
    atomicAdd(&stats[C + c], ss);
}

__global__ __launch_bounds__(256) void k_bn_fin(float* __restrict__ stats, int C) {
    int c = threadIdx.x;
    if (c < C) {
        const float invN = 1.0f / (float)NN;
        float mean = stats[c] * invN;
        float var = stats[C + c] * invN - mean * mean;
        stats[c] = mean;
        stats[C + c] = rsqrtf(var + BN_EPS);
    }
}

template <int C>
__global__ __launch_bounds__(256) void k_bn_apply(float* __restrict__ x,
                                                  const float* __restrict__ stats,
                                                  const float* __restrict__ g,
                                                  const float* __restrict__ be) {
    int i = blockIdx.x * 256 + threadIdx.x;
    if (i >= NN * C) return;
    int c = i & (C - 1);
    float v = (x[i] - stats[c]) * stats[C + c] * g[c] + be[c];
    x[i] = fmaxf(v, 0.0f);
}

// ---------------- edge MLP: one edge per lane ----------------
__global__ __launch_bounds__(256) void k_edge_mlp(const float* __restrict__ emb,
                                                  const int* __restrict__ src,
                                                  const int* __restrict__ dst,
                                                  const float* __restrict__ W1,
                                                  const float* __restrict__ b1,
                                                  const float* __restrict__ W2,
                                                  const float* __restrict__ b2,
                                                  const float* __restrict__ W3,
                                                  const float* __restrict__ b3,
                                                  float* __restrict__ out) {
    int e = blockIdx.x * 256 + threadIdx.x;
    if (e >= NE) return;
    int s = src[e], d = dst[e];
    const float4* es4 = reinterpret_cast<const float4*>(emb + (size_t)s * 64);
    const float4* ed4 = reinterpret_cast<const float4*>(emb + (size_t)d * 64);

    float h1[64];
    #pragma unroll
    for (int j = 0; j < 64; ++j) h1[j] = b1[j];

    for (int k4 = 0; k4 < 16; ++k4) {
        float4 ev = es4[k4];
        float evv[4] = {ev.x, ev.y, ev.z, ev.w};
        #pragma unroll
        for (int kk = 0; kk < 4; ++kk) {
            float ek = evv[kk];
            const float* wr = W1 + (size_t)(k4 * 4 + kk) * 64;
            #pragma unroll
            for (int j = 0; j < 64; ++j) h1[j] = fmaf(ek, wr[j], h1[j]);
        }
    }
    for (int k4 = 0; k4 < 16; ++k4) {
        float4 ev = ed4[k4];
        float evv[4] = {ev.x, ev.y, ev.z, ev.w};
        #pragma unroll
        for (int kk = 0; kk < 4; ++kk) {
            float ek = evv[kk];
            const float* wr = W1 + (size_t)(64 + k4 * 4 + kk) * 64;
            #pragma unroll
            for (int j = 0; j < 64; ++j) h1[j] = fmaf(ek, wr[j], h1[j]);
        }
    }

    float h2[32];
    #pragma unroll
    for (int j = 0; j < 32; ++j) h2[j] = b2[j];
    for (int k = 0; k < 64; ++k) {
        float hk = fmaxf(h1[k], 0.0f);
        const float* wr = W2 + (size_t)k * 32;
        #pragma unroll
        for (int j = 0; j < 32; ++j) h2[j] = fmaf(hk, wr[j], h2[j]);
    }

    float o0 = b3[0], o1 = b3[1];
    #pragma unroll
    for (int k = 0; k < 32; ++k) {
        float hk = fmaxf(h2[k], 0.0f);
        o0 = fmaf(hk, W3[2 * k + 0], o0);
        o1 = fmaf(hk, W3[2 * k + 1], o1);
    }
    *reinterpret_cast<float2*>(out + (size_t)2 * e) = make_float2(o0, o1);
}

// ---------------- launch ----------------
extern "C" void kernel_launch(void* const* d_in, const int* in_sizes, int n_in,
                              void* d_out, int out_size, void* d_ws, size_t ws_size,
                              hipStream_t stream) {
    const float* x    = (const float*)d_in[0];
    const int*   ei   = (const int*)d_in[1];
    const int*   src  = ei;
    const int*   dst  = ei + NE;
    const float* W1   = (const float*)d_in[2];
    const float* b1   = (const float*)d_in[3];
    const float* g1   = (const float*)d_in[4];
    const float* be1  = (const float*)d_in[5];
    const float* W2   = (const float*)d_in[6];
    const float* b2   = (const float*)d_in[7];
    const float* g2   = (const float*)d_in[8];
    const float* be2  = (const float*)d_in[9];
    const float* W3   = (const float*)d_in[10];
    const float* b3   = (const float*)d_in[11];
    const float* We1  = (const float*)d_in[12];
    const float* bme1 = (const float*)d_in[13];
    const float* We2  = (const float*)d_in[14];
    const float* bme2 = (const float*)d_in[15];
    const float* We3  = (const float*)d_in[16];
    const float* bme3 = (const float*)d_in[17];
    float* out = (float*)d_out;
    char* ws = (char*)d_ws;

    float* dsq      = (float*)ws;                         ws += NPAD * 4;
    float* dinv     = (float*)ws;                         ws += NPAD * 4;
    float* stats    = (float*)ws;                         ws += 1024 * 4;
    int*   cnt      = (int*)ws;                           ws += NPAD * 4;   // becomes cursor
    int*   row_start= (int*)ws;                           ws += (NPAD + 16) * 4;
    int*   csr_src  = (int*)ws;                           ws += NE * 4;
    float* bufH     = (float*)ws;                         ws += (size_t)NN * 256 * 4;
    float* bufO     = (float*)ws;

    const int nblkE = (NE + 255) / 256;
    const int nblkNode = (NN + 3) / 4;  // 1 wave per node, 4 waves per block

    // ---- CSR build + degree terms ----
    hipMemsetAsync(cnt, 0, NPAD * sizeof(int), stream);
    k_count_int<<<nblkE, 256, 0, stream>>>(dst, cnt);
    k_scan<<<1, 1024, 0, stream>>>(cnt, row_start, dsq, dinv);
    k_fill<<<nblkE, 256, 0, stream>>>(src, dst, cnt, csr_src);

    // ---- layer 1: 256 -> 256, agg, BN+relu ----
    {
        dim3 g(4, (NN + 63) / 64);
        k_gemm<<<g, 256, 0, stream>>>(x, W1, bufH, NN, 256, 256);
    }
    k_agg256<<<nblkNode, 256, 0, stream>>>(bufH, row_start, csr_src, dsq, dinv, b1, bufO);
    hipMemsetAsync(stats, 0, 1024 * sizeof(float), stream);
    k_bn_stats<256><<<256, 256, 0, stream>>>(bufO, stats);
    k_bn_fin<<<1, 256, 0, stream>>>(stats, 256);
    k_bn_apply<256><<<(NN * 256) / 256, 256, 0, stream>>>(bufO, stats, g1, be1);

    // ---- layer 2: 256 -> 64, agg, BN+relu ----
    {
        dim3 g(1, (NN + 63) / 64);
        k_gemm<<<g, 256, 0, stream>>>(bufO, W2, bufH, NN, 256, 64);
    }
    k_agg64<false><<<nblkNode, 256, 0, stream>>>(bufH, row_start, csr_src, dsq, dinv, b2, bufO);
    hipMemsetAsync(stats, 0, 1024 * sizeof(float), stream);
    k_bn_stats<64><<<256, 256, 0, stream>>>(bufO, stats);
    k_bn_fin<<<1, 256, 0, stream>>>(stats, 64);
    k_bn_apply<64><<<(NN * 64) / 256, 256, 0, stream>>>(bufO, stats, g2, be2);

    // ---- layer 3: 64 -> 64, agg + relu ----
    {
        dim3 g(1, (NN + 63) / 64);
        k_gemm<<<g, 256, 0, stream>>>(bufO, W3, bufH, NN, 64, 64);
    }
    k_agg64<true><<<nblkNode, 256, 0, stream>>>(bufH, row_start, csr_src, dsq, dinv, b3, bufO);

    // ---- layer 4: 64 -> 64 (same W3/b3, no relu) -> emb ----
    {
        dim3 g(1, (NN + 63) / 64);
        k_gemm<<<g, 256, 0, stream>>>(bufO, W3, bufH, NN, 64, 64);
    }
    k_agg64<false><<<nblkNode, 256, 0, stream>>>(bufH, row_start, csr_src, dsq, dinv, b3, bufO);

    // ---- edge MLP ----
    k_edge_mlp<<<nblkE, 256, 0, stream>>>(bufO, src, dst, We1, bme1, We2, bme2, We3, bme3, out);

    (void)in_sizes; (void)n_in; (void)out_size; (void)ws_size;
}

// Round 3
// 1095.198 us; speedup vs baseline: 3.5138x; 1.0625x over previous
//
#include <hip/hip_runtime.h>
#include <cstddef>

#define NN 50000
#define NE 800000
#define NPAD 50176
#define BN_EPS 1e-5f

// ---------------- CSR build ----------------
__global__ __launch_bounds__(256) void k_count_int(const int* __restrict__ dst,
                                                   int* __restrict__ cnt) {
    int e = blockIdx.x * 256 + threadIdx.x;
    if (e < NE) atomicAdd(&cnt[dst[e]], 1);
}

// single block, 1024 threads: exclusive scan of cnt -> row_start; cnt becomes cursor;
// also computes dsq = rsqrt(deg), dinv = 1/deg with deg = cnt+1 (self loop).
__global__ __launch_bounds__(1024) void k_scan(int* __restrict__ cnt,
                                               int* __restrict__ row_start,
                                               float* __restrict__ dsq,
                                               float* __restrict__ dinv) {
    __shared__ int part[1024];
    const int t = threadIdx.x;
    const int CHUNK = (NN + 1023) / 1024;
    int begin = t * CHUNK, end = min(begin + CHUNK, NN);
    int s = 0;
    for (int i = begin; i < end; ++i) s += cnt[i];
    part[t] = s;
    __syncthreads();
    for (int off = 1; off < 1024; off <<= 1) {
        int v = (t >= off) ? part[t - off] : 0;
        __syncthreads();
        part[t] += v;
        __syncthreads();
    }
    int running = (t == 0) ? 0 : part[t - 1];
    for (int i = begin; i < end; ++i) {
        int c = cnt[i];
        row_start[i] = running;
        cnt[i] = running;  // becomes the fill cursor
        running += c;
        float d = (float)c + 1.0f;
        dsq[i] = rsqrtf(d);
        dinv[i] = 1.0f / d;
    }
    if (t == 0) row_start[NN] = part[1023];
}

__global__ __launch_bounds__(256) void k_fill(const int* __restrict__ src,
                                              const int* __restrict__ dst,
                                              int* __restrict__ cursor,
                                              int* __restrict__ csr_src) {
    int e = blockIdx.x * 256 + threadIdx.x;
    if (e < NE) {
        int pos = atomicAdd(&cursor[dst[e]], 1);
        csr_src[pos] = src[e];
    }
}

// ---------------- fp32 tiled GEMM: C[M,N] = A[M,K] @ B[K,N] ----------------
__global__ __launch_bounds__(256) void k_gemm(const float* __restrict__ A,
                                              const float* __restrict__ B,
                                              float* __restrict__ C,
                                              int M, int K, int N) {
    __shared__ float As[16][68];
    __shared__ float Bs[16][68];
    const int tid = threadIdx.x;
    const int tx = tid & 15, ty = tid >> 4;
    const int row0 = blockIdx.y * 64, col0 = blockIdx.x * 64;
    float acc[4][4] = {};

    for (int kk = 0; kk < K; kk += 16) {
        #pragma unroll
        for (int i = 0; i < 4; ++i) {
            int idx = tid + i * 256;
            int m = idx >> 4, k = idx & 15;
            int gr = row0 + m;
            As[k][m] = (gr < M) ? A[(size_t)gr * K + kk + k] : 0.0f;
        }
        #pragma unroll
        for (int i = 0; i < 4; ++i) {
            int idx = tid + i * 256;
            int k = idx >> 6, n = idx & 63;
            Bs[k][n] = B[(size_t)(kk + k) * N + col0 + n];
        }
        __syncthreads();
        #pragma unroll
        for (int k = 0; k < 16; ++k) {
            float4 a4 = *reinterpret_cast<const float4*>(&As[k][ty * 4]);
            float4 b4 = *reinterpret_cast<const float4*>(&Bs[k][tx * 4]);
            float av[4] = {a4.x, a4.y, a4.z, a4.w};
            float bv[4] = {b4.x, b4.y, b4.z, b4.w};
            #pragma unroll
            for (int i = 0; i < 4; ++i)
                #pragma unroll
                for (int j = 0; j < 4; ++j)
                    acc[i][j] = fmaf(av[i], bv[j], acc[i][j]);
        }
        __syncthreads();
    }
    #pragma unroll
    for (int i = 0; i < 4; ++i) {
        int gr = row0 + ty * 4 + i;
        if (gr < M) {
            float4 v = make_float4(acc[i][0], acc[i][1], acc[i][2], acc[i][3]);
            *reinterpret_cast<float4*>(&C[(size_t)gr * N + col0 + tx * 4]) = v;
        }
    }
}

// ---------------- CSR aggregation, D=256: one wave per node, float4 lanes ----------------
// out[d] = dsq[d]*sum_{s in row} dsq[s]*h[s]  +  h[d]*dinv[d]  +  b
__global__ __launch_bounds__(256) void k_agg256(const float* __restrict__ h,
                                                const int* __restrict__ row_start,
                                                const int* __restrict__ csr_src,
                                                const float* __restrict__ dsq,
                                                const float* __restrict__ dinv,
                                                const float* __restrict__ b,
                                                float* __restrict__ out) {
    int d = blockIdx.x * 4 + (threadIdx.x >> 6);
    if (d >= NN) return;
    int lane = threadIdx.x & 63;
    int rs = row_start[d], re = row_start[d + 1];
    float4 acc = make_float4(0.f, 0.f, 0.f, 0.f);
    for (int j = rs; j < re; ++j) {
        int s = csr_src[j];
        float w = dsq[s];
        float4 v = *reinterpret_cast<const float4*>(h + (size_t)s * 256 + lane * 4);
        acc.x = fmaf(v.x, w, acc.x);
        acc.y = fmaf(v.y, w, acc.y);
        acc.z = fmaf(v.z, w, acc.z);
        acc.w = fmaf(v.w, w, acc.w);
    }
    float sd = dsq[d], di = dinv[d];
    float4 hv = *reinterpret_cast<const float4*>(h + (size_t)d * 256 + lane * 4);
    float4 bv = *reinterpret_cast<const float4*>(b + lane * 4);
    float4 o;
    o.x = fmaf(acc.x, sd, fmaf(hv.x, di, bv.x));
    o.y = fmaf(acc.y, sd, fmaf(hv.y, di, bv.y));
    o.z = fmaf(acc.z, sd, fmaf(hv.z, di, bv.z));
    o.w = fmaf(acc.w, sd, fmaf(hv.w, di, bv.w));
    *reinterpret_cast<float4*>(out + (size_t)d * 256 + lane * 4) = o;
}

// ---------------- CSR aggregation, D=64: one wave per node ----------------
template <bool RELU>
__global__ __launch_bounds__(256) void k_agg64(const float* __restrict__ h,
                                               const int* __restrict__ row_start,
                                               const int* __restrict__ csr_src,
                                               const float* __restrict__ dsq,
                                               const float* __restrict__ dinv,
                                               const float* __restrict__ b,
                                               float* __restrict__ out) {
    int d = blockIdx.x * 4 + (threadIdx.x >> 6);
    if (d >= NN) return;
    int lane = threadIdx.x & 63;
    int rs = row_start[d], re = row_start[d + 1];
    float acc = 0.0f;
    for (int j = rs; j < re; ++j) {
        int s = csr_src[j];
        acc = fmaf(h[(size_t)s * 64 + lane], dsq[s], acc);
    }
    float o = fmaf(acc, dsq[d], fmaf(h[(size_t)d * 64 + lane], dinv[d], b[lane]));
    if (RELU) o = fmaxf(o, 0.0f);
    out[(size_t)d * 64 + lane] = o;
}

// ---------------- BatchNorm ----------------
template <int C>
__global__ __launch_bounds__(256) void k_bn_stats(const float* __restrict__ x,
                                                  float* __restrict__ stats) {
    int c = threadIdx.x & (C - 1);
    int rstart = blockIdx.x * (256 / C) + (threadIdx.x / C);
    int rstride = gridDim.x * (256 / C);
    float s = 0.0f, ss = 0.0f;
    for (int r = rstart; r < NN; r += rstride) {
        float v = x[(size_t)r * C + c];
        s += v;
        ss += v * v;
    }
    atomicAdd(&stats[c], s);
    atomicAdd(&stats[C + c], ss);
}

__global__ __launch_bounds__(256) void k_bn_fin(float* __restrict__ stats, int C) {
    int c = threadIdx.x;
    if (c < C) {
        const float invN = 1.0f / (float)NN;
        float mean = stats[c] * invN;
        float var = stats[C + c] * invN - mean * mean;
        stats[c] = mean;
        stats[C + c] = rsqrtf(var + BN_EPS);
    }
}

template <int C>
__global__ __launch_bounds__(256) void k_bn_apply(float* __restrict__ x,
                                                  const float* __restrict__ stats,
                                                  const float* __restrict__ g,
                                                  const float* __restrict__ be) {
    int i = blockIdx.x * 256 + threadIdx.x;
    if (i >= NN * C) return;
    int c = i & (C - 1);
    float v = (x[i] - stats[c]) * stats[C + c] * g[c] + be[c];
    x[i] = fmaxf(v, 0.0f);
}

// ---------------- factored edge MLP ----------------
// h1 = relu(A[s] + B[d] + b1); h2 = relu(h1 @ W2 + b2); out = h2 @ W3 + b3
__global__ __launch_bounds__(256) void k_edge_mlp2(const float* __restrict__ A,
                                                   const float* __restrict__ B,
                                                   const int* __restrict__ src,
                                                   const int* __restrict__ dst,
                                                   const float* __restrict__ b1,
                                                   const float* __restrict__ W2,
                                                   const float* __restrict__ b2,
                                                   const float* __restrict__ W3,
                                                   const float* __restrict__ b3,
                                                   float* __restrict__ out) {
    int e = blockIdx.x * 256 + threadIdx.x;
    if (e >= NE) return;
    int s = src[e], d = dst[e];
    const float4* as4 = reinterpret_cast<const float4*>(A + (size_t)s * 64);
    const float4* bd4 = reinterpret_cast<const float4*>(B + (size_t)d * 64);

    float h2[32];
    #pragma unroll
    for (int j = 0; j < 32; ++j) h2[j] = b2[j];

    #pragma unroll
    for (int k4 = 0; k4 < 16; ++k4) {
        float4 av = as4[k4];
        float4 bv = bd4[k4];
        float h1v[4] = {av.x + bv.x, av.y + bv.y, av.z + bv.z, av.w + bv.w};
        #pragma unroll
        for (int kk = 0; kk < 4; ++kk) {
            int k = k4 * 4 + kk;
            float hk = fmaxf(h1v[kk] + b1[k], 0.0f);
            const float* wr = W2 + (size_t)k * 32;
            #pragma unroll
            for (int j = 0; j < 32; ++j) h2[j] = fmaf(hk, wr[j], h2[j]);
        }
    }

    float o0 = b3[0], o1 = b3[1];
    #pragma unroll
    for (int k = 0; k < 32; ++k) {
        float hk = fmaxf(h2[k], 0.0f);
        o0 = fmaf(hk, W3[2 * k + 0], o0);
        o1 = fmaf(hk, W3[2 * k + 1], o1);
    }
    *reinterpret_cast<float2*>(out + (size_t)2 * e) = make_float2(o0, o1);
}

// ---------------- launch ----------------
extern "C" void kernel_launch(void* const* d_in, const int* in_sizes, int n_in,
                              void* d_out, int out_size, void* d_ws, size_t ws_size,
                              hipStream_t stream) {
    const float* x    = (const float*)d_in[0];
    const int*   ei   = (const int*)d_in[1];
    const int*   src  = ei;
    const int*   dst  = ei + NE;
    const float* W1   = (const float*)d_in[2];
    const float* b1   = (const float*)d_in[3];
    const float* g1   = (const float*)d_in[4];
    const float* be1  = (const float*)d_in[5];
    const float* W2   = (const float*)d_in[6];
    const float* b2   = (const float*)d_in[7];
    const float* g2   = (const float*)d_in[8];
    const float* be2  = (const float*)d_in[9];
    const float* W3   = (const float*)d_in[10];
    const float* b3   = (const float*)d_in[11];
    const float* We1  = (const float*)d_in[12];
    const float* bme1 = (const float*)d_in[13];
    const float* We2  = (const float*)d_in[14];
    const float* bme2 = (const float*)d_in[15];
    const float* We3  = (const float*)d_in[16];
    const float* bme3 = (const float*)d_in[17];
    float* out = (float*)d_out;
    char* ws = (char*)d_ws;

    float* dsq      = (float*)ws;                         ws += NPAD * 4;
    float* dinv     = (float*)ws;                         ws += NPAD * 4;
    float* stats    = (float*)ws;                         ws += 1024 * 4;
    int*   cnt      = (int*)ws;                           ws += NPAD * 4;   // becomes cursor
    int*   row_start= (int*)ws;                           ws += (NPAD + 16) * 4;
    int*   csr_src  = (int*)ws;                           ws += NE * 4;
    float* bufH     = (float*)ws;                         ws += (size_t)NN * 256 * 4;
    float* bufO     = (float*)ws;

    const int nblkE = (NE + 255) / 256;
    const int nblkNode = (NN + 3) / 4;  // 1 wave per node, 4 waves per block

    // ---- CSR build + degree terms ----
    hipMemsetAsync(cnt, 0, NPAD * sizeof(int), stream);
    k_count_int<<<nblkE, 256, 0, stream>>>(dst, cnt);
    k_scan<<<1, 1024, 0, stream>>>(cnt, row_start, dsq, dinv);
    k_fill<<<nblkE, 256, 0, stream>>>(src, dst, cnt, csr_src);

    // ---- layer 1: 256 -> 256, agg, BN+relu ----
    {
        dim3 g(4, (NN + 63) / 64);
        k_gemm<<<g, 256, 0, stream>>>(x, W1, bufH, NN, 256, 256);
    }
    k_agg256<<<nblkNode, 256, 0, stream>>>(bufH, row_start, csr_src, dsq, dinv, b1, bufO);
    hipMemsetAsync(stats, 0, 1024 * sizeof(float), stream);
    k_bn_stats<256><<<256, 256, 0, stream>>>(bufO, stats);
    k_bn_fin<<<1, 256, 0, stream>>>(stats, 256);
    k_bn_apply<256><<<(NN * 256) / 256, 256, 0, stream>>>(bufO, stats, g1, be1);

    // ---- layer 2: 256 -> 64, agg, BN+relu ----
    {
        dim3 g(1, (NN + 63) / 64);
        k_gemm<<<g, 256, 0, stream>>>(bufO, W2, bufH, NN, 256, 64);
    }
    k_agg64<false><<<nblkNode, 256, 0, stream>>>(bufH, row_start, csr_src, dsq, dinv, b2, bufO);
    hipMemsetAsync(stats, 0, 1024 * sizeof(float), stream);
    k_bn_stats<64><<<256, 256, 0, stream>>>(bufO, stats);
    k_bn_fin<<<1, 256, 0, stream>>>(stats, 64);
    k_bn_apply<64><<<(NN * 64) / 256, 256, 0, stream>>>(bufO, stats, g2, be2);

    // ---- layer 3: 64 -> 64, agg + relu ----
    {
        dim3 g(1, (NN + 63) / 64);
        k_gemm<<<g, 256, 0, stream>>>(bufO, W3, bufH, NN, 64, 64);
    }
    k_agg64<true><<<nblkNode, 256, 0, stream>>>(bufH, row_start, csr_src, dsq, dinv, b3, bufO);

    // ---- layer 4: 64 -> 64 (same W3/b3, no relu) -> emb in bufO ----
    {
        dim3 g(1, (NN + 63) / 64);
        k_gemm<<<g, 256, 0, stream>>>(bufO, W3, bufH, NN, 64, 64);
    }
    k_agg64<false><<<nblkNode, 256, 0, stream>>>(bufH, row_start, csr_src, dsq, dinv, b3, bufO);

    // ---- edge MLP, factored layer 1: A = emb @ We1[0:64], B = emb @ We1[64:128] ----
    float* Abuf = bufH;                       // bufH is dead now; reuse
    float* Bbuf = bufH + (size_t)NN * 64;
    {
        dim3 g(1, (NN + 63) / 64);
        k_gemm<<<g, 256, 0, stream>>>(bufO, We1, Abuf, NN, 64, 64);
        k_gemm<<<g, 256, 0, stream>>>(bufO, We1 + (size_t)64 * 64, Bbuf, NN, 64, 64);
    }
    k_edge_mlp2<<<nblkE, 256, 0, stream>>>(Abuf, Bbuf, src, dst, bme1, We2, bme2, We3, bme3, out);

    (void)in_sizes; (void)n_in; (void)out_size; (void)ws_size;
}

// Round 4
// 930.551 us; speedup vs baseline: 4.1356x; 1.1769x over previous
//
#include <hip/hip_runtime.h>
#include <cstddef>

#define NN 50000
#define NE 800000
#define NPAD 50176
#define SCAN_BLOCKS 196   // ceil(NN/256)
#define BN_EPS 1e-5f

// ---------------- CSR build ----------------
__global__ __launch_bounds__(256) void k_count_int(const int* __restrict__ dst,
                                                   int* __restrict__ cnt) {
    int e = blockIdx.x * 256 + threadIdx.x;
    if (e < NE) atomicAdd(&cnt[dst[e]], 1);
}

// per-block sums of cnt
__global__ __launch_bounds__(256) void k_bsum(const int* __restrict__ cnt,
                                              int* __restrict__ bsum) {
    __shared__ int red[4];
    int i = blockIdx.x * 256 + threadIdx.x;
    int v = (i < NN) ? cnt[i] : 0;
    #pragma unroll
    for (int off = 32; off > 0; off >>= 1) v += __shfl_down(v, off, 64);
    int lane = threadIdx.x & 63, w = threadIdx.x >> 6;
    if (lane == 0) red[w] = v;
    __syncthreads();
    if (threadIdx.x == 0) bsum[blockIdx.x] = red[0] + red[1] + red[2] + red[3];
}

// single small block: exclusive scan of the 196 block sums in-place
__global__ __launch_bounds__(256) void k_scan_bsum(int* __restrict__ bsum) {
    __shared__ int tmp[256];
    int t = threadIdx.x;
    int v = (t < SCAN_BLOCKS) ? bsum[t] : 0;
    tmp[t] = v;
    __syncthreads();
    #pragma unroll
    for (int off = 1; off < 256; off <<= 1) {
        int u = (t >= off) ? tmp[t - off] : 0;
        __syncthreads();
        tmp[t] += u;
        __syncthreads();
    }
    if (t < SCAN_BLOCKS) bsum[t] = tmp[t] - v;  // exclusive
}

// per-block exclusive scan + global offset; also emits cursor, dsq, dinv
__global__ __launch_bounds__(256) void k_scan_fin(const int* __restrict__ cnt,
                                                  const int* __restrict__ bsum,
                                                  int* __restrict__ row_start,
                                                  int* __restrict__ cursor,
                                                  float* __restrict__ dsq,
                                                  float* __restrict__ dinv) {
    __shared__ int tmp[256];
    int t = threadIdx.x;
    int i = blockIdx.x * 256 + t;
    int c = (i < NN) ? cnt[i] : 0;
    tmp[t] = c;
    __syncthreads();
    #pragma unroll
    for (int off = 1; off < 256; off <<= 1) {
        int u = (t >= off) ? tmp[t - off] : 0;
        __syncthreads();
        tmp[t] += u;
        __syncthreads();
    }
    int excl = tmp[t] - c + bsum[blockIdx.x];
    if (i < NN) {
        row_start[i] = excl;
        cursor[i] = excl;
        float d = (float)c + 1.0f;
        dsq[i] = rsqrtf(d);
        dinv[i] = 1.0f / d;
    }
    if (i == 0) row_start[NN] = NE;
}

__global__ __launch_bounds__(256) void k_fill(const int* __restrict__ src,
                                              const int* __restrict__ dst,
                                              int* __restrict__ cursor,
                                              int* __restrict__ csr_src) {
    int e = blockIdx.x * 256 + threadIdx.x;
    if (e < NE) {
        int pos = atomicAdd(&cursor[dst[e]], 1);
        csr_src[pos] = src[e];
    }
}

// ---------------- fp32 tiled GEMM: C[M,N] = A[M,K] @ B[K,N] ----------------
__global__ __launch_bounds__(256) void k_gemm(const float* __restrict__ A,
                                              const float* __restrict__ B,
                                              float* __restrict__ C,
                                              int M, int K, int N) {
    __shared__ float As[16][68];
    __shared__ float Bs[16][68];
    const int tid = threadIdx.x;
    const int tx = tid & 15, ty = tid >> 4;
    const int row0 = blockIdx.y * 64, col0 = blockIdx.x * 64;
    float acc[4][4] = {};

    for (int kk = 0; kk < K; kk += 16) {
        #pragma unroll
        for (int i = 0; i < 4; ++i) {
            int idx = tid + i * 256;
            int m = idx >> 4, k = idx & 15;
            int gr = row0 + m;
            As[k][m] = (gr < M) ? A[(size_t)gr * K + kk + k] : 0.0f;
        }
        #pragma unroll
        for (int i = 0; i < 4; ++i) {
            int idx = tid + i * 256;
            int k = idx >> 6, n = idx & 63;
            Bs[k][n] = B[(size_t)(kk + k) * N + col0 + n];
        }
        __syncthreads();
        #pragma unroll
        for (int k = 0; k < 16; ++k) {
            float4 a4 = *reinterpret_cast<const float4*>(&As[k][ty * 4]);
            float4 b4 = *reinterpret_cast<const float4*>(&Bs[k][tx * 4]);
            float av[4] = {a4.x, a4.y, a4.z, a4.w};
            float bv[4] = {b4.x, b4.y, b4.z, b4.w};
            #pragma unroll
            for (int i = 0; i < 4; ++i)
                #pragma unroll
                for (int j = 0; j < 4; ++j)
                    acc[i][j] = fmaf(av[i], bv[j], acc[i][j]);
        }
        __syncthreads();
    }
    #pragma unroll
    for (int i = 0; i < 4; ++i) {
        int gr = row0 + ty * 4 + i;
        if (gr < M) {
            float4 v = make_float4(acc[i][0], acc[i][1], acc[i][2], acc[i][3]);
            *reinterpret_cast<float4*>(&C[(size_t)gr * N + col0 + tx * 4]) = v;
        }
    }
}

// ---------------- CSR aggregation, D=256 ----------------
__global__ __launch_bounds__(256) void k_agg256(const float* __restrict__ h,
                                                const int* __restrict__ row_start,
                                                const int* __restrict__ csr_src,
                                                const float* __restrict__ dsq,
                                                const float* __restrict__ dinv,
                                                const float* __restrict__ b,
                                                float* __restrict__ out) {
    int d = blockIdx.x * 4 + (threadIdx.x >> 6);
    if (d >= NN) return;
    int lane = threadIdx.x & 63;
    int rs = row_start[d], re = row_start[d + 1];
    float4 acc = make_float4(0.f, 0.f, 0.f, 0.f);
    for (int j = rs; j < re; ++j) {
        int s = csr_src[j];
        float w = dsq[s];
        float4 v = *reinterpret_cast<const float4*>(h + (size_t)s * 256 + lane * 4);
        acc.x = fmaf(v.x, w, acc.x);
        acc.y = fmaf(v.y, w, acc.y);
        acc.z = fmaf(v.z, w, acc.z);
        acc.w = fmaf(v.w, w, acc.w);
    }
    float sd = dsq[d], di = dinv[d];
    float4 hv = *reinterpret_cast<const float4*>(h + (size_t)d * 256 + lane * 4);
    float4 bv = *reinterpret_cast<const float4*>(b + lane * 4);
    float4 o;
    o.x = fmaf(acc.x, sd, fmaf(hv.x, di, bv.x));
    o.y = fmaf(acc.y, sd, fmaf(hv.y, di, bv.y));
    o.z = fmaf(acc.z, sd, fmaf(hv.z, di, bv.z));
    o.w = fmaf(acc.w, sd, fmaf(hv.w, di, bv.w));
    *reinterpret_cast<float4*>(out + (size_t)d * 256 + lane * 4) = o;
}

// ---------------- CSR aggregation, D=64 ----------------
template <bool RELU>
__global__ __launch_bounds__(256) void k_agg64(const float* __restrict__ h,
                                               const int* __restrict__ row_start,
                                               const int* __restrict__ csr_src,
                                               const float* __restrict__ dsq,
                                               const float* __restrict__ dinv,
                                               const float* __restrict__ b,
                                               float* __restrict__ out) {
    int d = blockIdx.x * 4 + (threadIdx.x >> 6);
    if (d >= NN) return;
    int lane = threadIdx.x & 63;
    int rs = row_start[d], re = row_start[d + 1];
    float acc = 0.0f;
    for (int j = rs; j < re; ++j) {
        int s = csr_src[j];
        acc = fmaf(h[(size_t)s * 64 + lane], dsq[s], acc);
    }
    float o = fmaf(acc, dsq[d], fmaf(h[(size_t)d * 64 + lane], dinv[d], b[lane]));
    if (RELU) o = fmaxf(o, 0.0f);
    out[(size_t)d * 64 + lane] = o;
}

// ---------------- BatchNorm ----------------
template <int C>
__global__ __launch_bounds__(256) void k_bn_stats(const float* __restrict__ x,
                                                  float* __restrict__ stats) {
    int c = threadIdx.x & (C - 1);
    int rstart = blockIdx.x * (256 / C) + (threadIdx.x / C);
    int rstride = gridDim.x * (256 / C);
    float s = 0.0f, ss = 0.0f;
    for (int r = rstart; r < NN; r += rstride) {
        float v = x[(size_t)r * C + c];
        s += v;
        ss += v * v;
    }
    atomicAdd(&stats[c], s);
    atomicAdd(&stats[C + c], ss);
}

__global__ __launch_bounds__(256) void k_bn_fin(float* __restrict__ stats, int C) {
    int c = threadIdx.x;
    if (c < C) {
        const float invN = 1.0f / (float)NN;
        float mean = stats[c] * invN;
        float var = stats[C + c] * invN - mean * mean;
        stats[c] = mean;
        stats[C + c] = rsqrtf(var + BN_EPS);
    }
}

template <int C>
__global__ __launch_bounds__(256) void k_bn_apply(float* __restrict__ x,
                                                  const float* __restrict__ stats,
                                                  const float* __restrict__ g,
                                                  const float* __restrict__ be) {
    int i = blockIdx.x * 256 + threadIdx.x;
    if (i >= NN * C) return;
    int c = i & (C - 1);
    float v = (x[i] - stats[c]) * stats[C + c] * g[c] + be[c];
    x[i] = fmaxf(v, 0.0f);
}

// ---------------- factored edge MLP ----------------
__global__ __launch_bounds__(256) void k_edge_mlp2(const float* __restrict__ A,
                                                   const float* __restrict__ B,
                                                   const int* __restrict__ src,
                                                   const int* __restrict__ dst,
                                                   const float* __restrict__ b1,
                                                   const float* __restrict__ W2,
                                                   const float* __restrict__ b2,
                                                   const float* __restrict__ W3,
                                                   const float* __restrict__ b3,
                                                   float* __restrict__ out) {
    int e = blockIdx.x * 256 + threadIdx.x;
    if (e >= NE) return;
    int s = src[e], d = dst[e];
    const float4* as4 = reinterpret_cast<const float4*>(A + (size_t)s * 64);
    const float4* bd4 = reinterpret_cast<const float4*>(B + (size_t)d * 64);

    float h2[32];
    #pragma unroll
    for (int j = 0; j < 32; ++j) h2[j] = b2[j];

    #pragma unroll
    for (int k4 = 0; k4 < 16; ++k4) {
        float4 av = as4[k4];
        float4 bv = bd4[k4];
        float h1v[4] = {av.x + bv.x, av.y + bv.y, av.z + bv.z, av.w + bv.w};
        #pragma unroll
        for (int kk = 0; kk < 4; ++kk) {
            int k = k4 * 4 + kk;
            float hk = fmaxf(h1v[kk] + b1[k], 0.0f);
            const float* wr = W2 + (size_t)k * 32;
            #pragma unroll
            for (int j = 0; j < 32; ++j) h2[j] = fmaf(hk, wr[j], h2[j]);
        }
    }

    float o0 = b3[0], o1 = b3[1];
    #pragma unroll
    for (int k = 0; k < 32; ++k) {
        float hk = fmaxf(h2[k], 0.0f);
        o0 = fmaf(hk, W3[2 * k + 0], o0);
        o1 = fmaf(hk, W3[2 * k + 1], o1);
    }
    *reinterpret_cast<float2*>(out + (size_t)2 * e) = make_float2(o0, o1);
}

// ---------------- launch ----------------
extern "C" void kernel_launch(void* const* d_in, const int* in_sizes, int n_in,
                              void* d_out, int out_size, void* d_ws, size_t ws_size,
                              hipStream_t stream) {
    const float* x    = (const float*)d_in[0];
    const int*   ei   = (const int*)d_in[1];
    const int*   src  = ei;
    const int*   dst  = ei + NE;
    const float* W1   = (const float*)d_in[2];
    const float* b1   = (const float*)d_in[3];
    const float* g1   = (const float*)d_in[4];
    const float* be1  = (const float*)d_in[5];
    const float* W2   = (const float*)d_in[6];
    const float* b2   = (const float*)d_in[7];
    const float* g2   = (const float*)d_in[8];
    const float* be2  = (const float*)d_in[9];
    const float* W3   = (const float*)d_in[10];
    const float* b3   = (const float*)d_in[11];
    const float* We1  = (const float*)d_in[12];
    const float* bme1 = (const float*)d_in[13];
    const float* We2  = (const float*)d_in[14];
    const float* bme2 = (const float*)d_in[15];
    const float* We3  = (const float*)d_in[16];
    const float* bme3 = (const float*)d_in[17];
    float* out = (float*)d_out;
    char* ws = (char*)d_ws;

    float* dsq      = (float*)ws;                         ws += NPAD * 4;
    float* dinv     = (float*)ws;                         ws += NPAD * 4;
    float* stats    = (float*)ws;                         ws += 1024 * 4;
    int*   cnt      = (int*)ws;                           ws += NPAD * 4;
    int*   cursor   = (int*)ws;                           ws += NPAD * 4;
    int*   bsum     = (int*)ws;                           ws += 256 * 4;
    int*   row_start= (int*)ws;                           ws += (NPAD + 16) * 4;
    int*   csr_src  = (int*)ws;                           ws += NE * 4;
    float* bufH     = (float*)ws;                         ws += (size_t)NN * 256 * 4;
    float* bufO     = (float*)ws;

    const int nblkE = (NE + 255) / 256;
    const int nblkNode = (NN + 3) / 4;  // 1 wave per node, 4 waves per block

    // ---- CSR build + degree terms (hierarchical scan) ----
    hipMemsetAsync(cnt, 0, NPAD * sizeof(int), stream);
    k_count_int<<<nblkE, 256, 0, stream>>>(dst, cnt);
    k_bsum<<<SCAN_BLOCKS, 256, 0, stream>>>(cnt, bsum);
    k_scan_bsum<<<1, 256, 0, stream>>>(bsum);
    k_scan_fin<<<SCAN_BLOCKS, 256, 0, stream>>>(cnt, bsum, row_start, cursor, dsq, dinv);
    k_fill<<<nblkE, 256, 0, stream>>>(src, dst, cursor, csr_src);

    // ---- layer 1: 256 -> 256, agg, BN+relu ----
    {
        dim3 g(4, (NN + 63) / 64);
        k_gemm<<<g, 256, 0, stream>>>(x, W1, bufH, NN, 256, 256);
    }
    k_agg256<<<nblkNode, 256, 0, stream>>>(bufH, row_start, csr_src, dsq, dinv, b1, bufO);
    hipMemsetAsync(stats, 0, 1024 * sizeof(float), stream);
    k_bn_stats<256><<<256, 256, 0, stream>>>(bufO, stats);
    k_bn_fin<<<1, 256, 0, stream>>>(stats, 256);
    k_bn_apply<256><<<(NN * 256) / 256, 256, 0, stream>>>(bufO, stats, g1, be1);

    // ---- layer 2: 256 -> 64, agg, BN+relu ----
    {
        dim3 g(1, (NN + 63) / 64);
        k_gemm<<<g, 256, 0, stream>>>(bufO, W2, bufH, NN, 256, 64);
    }
    k_agg64<false><<<nblkNode, 256, 0, stream>>>(bufH, row_start, csr_src, dsq, dinv, b2, bufO);
    hipMemsetAsync(stats, 0, 1024 * sizeof(float), stream);
    k_bn_stats<64><<<256, 256, 0, stream>>>(bufO, stats);
    k_bn_fin<<<1, 256, 0, stream>>>(stats, 64);
    k_bn_apply<64><<<(NN * 64) / 256, 256, 0, stream>>>(bufO, stats, g2, be2);

    // ---- layer 3: 64 -> 64, agg + relu ----
    {
        dim3 g(1, (NN + 63) / 64);
        k_gemm<<<g, 256, 0, stream>>>(bufO, W3, bufH, NN, 64, 64);
    }
    k_agg64<true><<<nblkNode, 256, 0, stream>>>(bufH, row_start, csr_src, dsq, dinv, b3, bufO);

    // ---- layer 4: 64 -> 64 (same W3/b3, no relu) -> emb in bufO ----
    {
        dim3 g(1, (NN + 63) / 64);
        k_gemm<<<g, 256, 0, stream>>>(bufO, W3, bufH, NN, 64, 64);
    }
    k_agg64<false><<<nblkNode, 256, 0, stream>>>(bufH, row_start, csr_src, dsq, dinv, b3, bufO);

    // ---- edge MLP, factored layer 1 ----
    float* Abuf = bufH;
    float* Bbuf = bufH + (size_t)NN * 64;
    {
        dim3 g(1, (NN + 63) / 64);
        k_gemm<<<g, 256, 0, stream>>>(bufO, We1, Abuf, NN, 64, 64);
        k_gemm<<<g, 256, 0, stream>>>(bufO, We1 + (size_t)64 * 64, Bbuf, NN, 64, 64);
    }
    k_edge_mlp2<<<nblkE, 256, 0, stream>>>(Abuf, Bbuf, src, dst, bme1, We2, bme2, We3, bme3, out);

    (void)in_sizes; (void)n_in; (void)out_size; (void)ws_size;
}

// Round 5
// 873.587 us; speedup vs baseline: 4.4052x; 1.0652x over previous
//
#include <hip/hip_runtime.h>
#include <cstddef>

#define NN 50000
#define NE 800000
#define NPAD 50176
#define SCAN_BLOCKS 196   // ceil(NN/256)
#define BN_EPS 1e-5f
#define EB 192            // edges per block in edge MLP

// ---------------- CSR build ----------------
__global__ __launch_bounds__(256) void k_count_int(const int* __restrict__ dst,
                                                   int* __restrict__ cnt) {
    int e = blockIdx.x * 256 + threadIdx.x;
    if (e < NE) atomicAdd(&cnt[dst[e]], 1);
}

__global__ __launch_bounds__(256) void k_bsum(const int* __restrict__ cnt,
                                              int* __restrict__ bsum) {
    __shared__ int red[4];
    int i = blockIdx.x * 256 + threadIdx.x;
    int v = (i < NN) ? cnt[i] : 0;
    #pragma unroll
    for (int off = 32; off > 0; off >>= 1) v += __shfl_down(v, off, 64);
    int lane = threadIdx.x & 63, w = threadIdx.x >> 6;
    if (lane == 0) red[w] = v;
    __syncthreads();
    if (threadIdx.x == 0) bsum[blockIdx.x] = red[0] + red[1] + red[2] + red[3];
}

__global__ __launch_bounds__(256) void k_scan_bsum(int* __restrict__ bsum) {
    __shared__ int tmp[256];
    int t = threadIdx.x;
    int v = (t < SCAN_BLOCKS) ? bsum[t] : 0;
    tmp[t] = v;
    __syncthreads();
    #pragma unroll
    for (int off = 1; off < 256; off <<= 1) {
        int u = (t >= off) ? tmp[t - off] : 0;
        __syncthreads();
        tmp[t] += u;
        __syncthreads();
    }
    if (t < SCAN_BLOCKS) bsum[t] = tmp[t] - v;  // exclusive
}

__global__ __launch_bounds__(256) void k_scan_fin(const int* __restrict__ cnt,
                                                  const int* __restrict__ bsum,
                                                  int* __restrict__ row_start,
                                                  int* __restrict__ cursor,
                                                  float* __restrict__ dsq,
                                                  float* __restrict__ dinv) {
    __shared__ int tmp[256];
    int t = threadIdx.x;
    int i = blockIdx.x * 256 + t;
    int c = (i < NN) ? cnt[i] : 0;
    tmp[t] = c;
    __syncthreads();
    #pragma unroll
    for (int off = 1; off < 256; off <<= 1) {
        int u = (t >= off) ? tmp[t - off] : 0;
        __syncthreads();
        tmp[t] += u;
        __syncthreads();
    }
    int excl = tmp[t] - c + bsum[blockIdx.x];
    if (i < NN) {
        row_start[i] = excl;
        cursor[i] = excl;
        float d = (float)c + 1.0f;
        dsq[i] = rsqrtf(d);
        dinv[i] = 1.0f / d;
    }
    if (i == 0) row_start[NN] = NE;
}

__global__ __launch_bounds__(256) void k_fill(const int* __restrict__ src,
                                              const int* __restrict__ dst,
                                              int* __restrict__ cursor,
                                              int* __restrict__ csr_src) {
    int e = blockIdx.x * 256 + threadIdx.x;
    if (e < NE) {
        int pos = atomicAdd(&cursor[dst[e]], 1);
        csr_src[pos] = src[e];
    }
}

// ---------------- fp32 tiled GEMM, 64x64 tile, optional fused BN+relu on A ----------------
template <bool BN>
__global__ __launch_bounds__(256) void k_gemm(const float* __restrict__ A,
                                              const float* __restrict__ B,
                                              float* __restrict__ C,
                                              int M, int K, int N,
                                              const float* __restrict__ stats,
                                              const float* __restrict__ g,
                                              const float* __restrict__ be) {
    __shared__ float As[16][68];
    __shared__ float Bs[16][68];
    const int tid = threadIdx.x;
    const int tx = tid & 15, ty = tid >> 4;
    const int row0 = blockIdx.y * 64, col0 = blockIdx.x * 64;
    float acc[4][4] = {};

    for (int kk = 0; kk < K; kk += 16) {
        #pragma unroll
        for (int i = 0; i < 4; ++i) {
            int idx = tid + i * 256;
            int m = idx >> 4, k = idx & 15;
            int gr = row0 + m;
            float v = (gr < M) ? A[(size_t)gr * K + kk + k] : 0.0f;
            if (BN) {
                int c = kk + k;
                v = fmaxf((v - stats[c]) * stats[K + c] * g[c] + be[c], 0.0f);
            }
            As[k][m] = v;
        }
        #pragma unroll
        for (int i = 0; i < 4; ++i) {
            int idx = tid + i * 256;
            int k = idx >> 6, n = idx & 63;
            Bs[k][n] = B[(size_t)(kk + k) * N + col0 + n];
        }
        __syncthreads();
        #pragma unroll
        for (int k = 0; k < 16; ++k) {
            float4 a4 = *reinterpret_cast<const float4*>(&As[k][ty * 4]);
            float4 b4 = *reinterpret_cast<const float4*>(&Bs[k][tx * 4]);
            float av[4] = {a4.x, a4.y, a4.z, a4.w};
            float bv[4] = {b4.x, b4.y, b4.z, b4.w};
            #pragma unroll
            for (int i = 0; i < 4; ++i)
                #pragma unroll
                for (int j = 0; j < 4; ++j)
                    acc[i][j] = fmaf(av[i], bv[j], acc[i][j]);
        }
        __syncthreads();
    }
    #pragma unroll
    for (int i = 0; i < 4; ++i) {
        int gr = row0 + ty * 4 + i;
        if (gr < M) {
            float4 v = make_float4(acc[i][0], acc[i][1], acc[i][2], acc[i][3]);
            *reinterpret_cast<float4*>(&C[(size_t)gr * N + col0 + tx * 4]) = v;
        }
    }
}

// ---------------- fp32 GEMM, 128x128 tile, 8x8 micro (split 4+4), BK=8 ----------------
// Requires N % 128 == 0, K % 8 == 0.
__global__ __launch_bounds__(256) void k_gemm128(const float* __restrict__ A,
                                                 const float* __restrict__ B,
                                                 float* __restrict__ C,
                                                 int M, int K, int N) {
    __shared__ float As[8][132];
    __shared__ float Bs[8][132];
    const int tid = threadIdx.x;
    const int tx = tid & 15, ty = tid >> 4;
    const int row0 = blockIdx.y * 128, col0 = blockIdx.x * 128;
    float acc[8][8] = {};

    for (int kk = 0; kk < K; kk += 8) {
        // stage A: 128 rows x 8 k
        {
            int m = tid >> 1;
            int k4 = (tid & 1) * 4;
            int gr = row0 + m;
            float4 v = make_float4(0.f, 0.f, 0.f, 0.f);
            if (gr < M) v = *reinterpret_cast<const float4*>(&A[(size_t)gr * K + kk + k4]);
            As[k4 + 0][m] = v.x;
            As[k4 + 1][m] = v.y;
            As[k4 + 2][m] = v.z;
            As[k4 + 3][m] = v.w;
        }
        // stage B: 8 k x 128 cols
        {
            int k = tid >> 5;
            int n = (tid & 31) * 4;
            *reinterpret_cast<float4*>(&Bs[k][n]) =
                *reinterpret_cast<const float4*>(&B[(size_t)(kk + k) * N + col0 + n]);
        }
        __syncthreads();
        #pragma unroll
        for (int k = 0; k < 8; ++k) {
            float a[8], b[8];
            *reinterpret_cast<float4*>(&a[0]) = *reinterpret_cast<const float4*>(&As[k][ty * 4]);
            *reinterpret_cast<float4*>(&a[4]) = *reinterpret_cast<const float4*>(&As[k][64 + ty * 4]);
            *reinterpret_cast<float4*>(&b[0]) = *reinterpret_cast<const float4*>(&Bs[k][tx * 4]);
            *reinterpret_cast<float4*>(&b[4]) = *reinterpret_cast<const float4*>(&Bs[k][64 + tx * 4]);
            #pragma unroll
            for (int i = 0; i < 8; ++i)
                #pragma unroll
                for (int j = 0; j < 8; ++j)
                    acc[i][j] = fmaf(a[i], b[j], acc[i][j]);
        }
        __syncthreads();
    }
    #pragma unroll
    for (int i = 0; i < 8; ++i) {
        int gr = row0 + (i < 4 ? ty * 4 + i : 64 + ty * 4 + (i - 4));
        if (gr < M) {
            float4 v0 = make_float4(acc[i][0], acc[i][1], acc[i][2], acc[i][3]);
            float4 v1 = make_float4(acc[i][4], acc[i][5], acc[i][6], acc[i][7]);
            *reinterpret_cast<float4*>(&C[(size_t)gr * N + col0 + tx * 4]) = v0;
            *reinterpret_cast<float4*>(&C[(size_t)gr * N + col0 + 64 + tx * 4]) = v1;
        }
    }
}

// ---------------- CSR aggregation, D=256 ----------------
__global__ __launch_bounds__(256) void k_agg256(const float* __restrict__ h,
                                                const int* __restrict__ row_start,
                                                const int* __restrict__ csr_src,
                                                const float* __restrict__ dsq,
                                                const float* __restrict__ dinv,
                                                const float* __restrict__ b,
                                                float* __restrict__ out) {
    int d = blockIdx.x * 4 + (threadIdx.x >> 6);
    if (d >= NN) return;
    int lane = threadIdx.x & 63;
    int rs = row_start[d], re = row_start[d + 1];
    float4 acc = make_float4(0.f, 0.f, 0.f, 0.f);
    for (int j = rs; j < re; ++j) {
        int s = csr_src[j];
        float w = dsq[s];
        float4 v = *reinterpret_cast<const float4*>(h + (size_t)s * 256 + lane * 4);
        acc.x = fmaf(v.x, w, acc.x);
        acc.y = fmaf(v.y, w, acc.y);
        acc.z = fmaf(v.z, w, acc.z);
        acc.w = fmaf(v.w, w, acc.w);
    }
    float sd = dsq[d], di = dinv[d];
    float4 hv = *reinterpret_cast<const float4*>(h + (size_t)d * 256 + lane * 4);
    float4 bv = *reinterpret_cast<const float4*>(b + lane * 4);
    float4 o;
    o.x = fmaf(acc.x, sd, fmaf(hv.x, di, bv.x));
    o.y = fmaf(acc.y, sd, fmaf(hv.y, di, bv.y));
    o.z = fmaf(acc.z, sd, fmaf(hv.z, di, bv.z));
    o.w = fmaf(acc.w, sd, fmaf(hv.w, di, bv.w));
    *reinterpret_cast<float4*>(out + (size_t)d * 256 + lane * 4) = o;
}

// ---------------- CSR aggregation, D=64 ----------------
template <bool RELU>
__global__ __launch_bounds__(256) void k_agg64(const float* __restrict__ h,
                                               const int* __restrict__ row_start,
                                               const int* __restrict__ csr_src,
                                               const float* __restrict__ dsq,
                                               const float* __restrict__ dinv,
                                               const float* __restrict__ b,
                                               float* __restrict__ out) {
    int d = blockIdx.x * 4 + (threadIdx.x >> 6);
    if (d >= NN) return;
    int lane = threadIdx.x & 63;
    int rs = row_start[d], re = row_start[d + 1];
    float acc = 0.0f;
    for (int j = rs; j < re; ++j) {
        int s = csr_src[j];
        acc = fmaf(h[(size_t)s * 64 + lane], dsq[s], acc);
    }
    float o = fmaf(acc, dsq[d], fmaf(h[(size_t)d * 64 + lane], dinv[d], b[lane]));
    if (RELU) o = fmaxf(o, 0.0f);
    out[(size_t)d * 64 + lane] = o;
}

// ---------------- BatchNorm stats ----------------
template <int C>
__global__ __launch_bounds__(256) void k_bn_stats(const float* __restrict__ x,
                                                  float* __restrict__ stats) {
    int c = threadIdx.x & (C - 1);
    int rstart = blockIdx.x * (256 / C) + (threadIdx.x / C);
    int rstride = gridDim.x * (256 / C);
    float s = 0.0f, ss = 0.0f;
    for (int r = rstart; r < NN; r += rstride) {
        float v = x[(size_t)r * C + c];
        s += v;
        ss += v * v;
    }
    atomicAdd(&stats[c], s);
    atomicAdd(&stats[C + c], ss);
}

__global__ __launch_bounds__(256) void k_bn_fin(float* __restrict__ stats, int C) {
    int c = threadIdx.x;
    if (c < C) {
        const float invN = 1.0f / (float)NN;
        float mean = stats[c] * invN;
        float var = stats[C + c] * invN - mean * mean;
        stats[c] = mean;
        stats[C + c] = rsqrtf(var + BN_EPS);
    }
}

// ---------------- edge MLP: block-batched, coalesced gather ----------------
// phase 1: waves gather rows coalesced, h1 = relu(A[s]+B[d]+b1) -> LDS
// phase 2: one edge per thread computes 64->32->2 tail from LDS
__global__ __launch_bounds__(EB) void k_edge_mlp3(const float* __restrict__ A,
                                                  const float* __restrict__ B,
                                                  const int* __restrict__ src,
                                                  const int* __restrict__ dst,
                                                  const float* __restrict__ b1,
                                                  const float* __restrict__ W2,
                                                  const float* __restrict__ b2,
                                                  const float* __restrict__ W3,
                                                  const float* __restrict__ b3,
                                                  float* __restrict__ out) {
    __shared__ float h1s[EB][65];
    const int tid = threadIdx.x;
    const int w = tid >> 6, lane = tid & 63;
    const int base = blockIdx.x * EB + w * 64;

    int ee = base + lane;
    if (ee >= NE) ee = NE - 1;
    int se = src[ee];
    int de = dst[ee];
    float b1v = b1[lane];

    #pragma unroll 8
    for (int i = 0; i < 64; ++i) {
        int s = __shfl(se, i, 64);
        int d = __shfl(de, i, 64);
        float v = A[(size_t)s * 64 + lane] + B[(size_t)d * 64 + lane] + b1v;
        h1s[w * 64 + i][lane] = fmaxf(v, 0.0f);
    }
    __syncthreads();

    int e = blockIdx.x * EB + tid;
    if (e >= NE) return;

    float h2[32];
    #pragma unroll
    for (int j = 0; j < 32; ++j) h2[j] = b2[j];
    #pragma unroll
    for (int k = 0; k < 64; ++k) {
        float hk = h1s[tid][k];
        const float* wr = W2 + (size_t)k * 32;
        #pragma unroll
        for (int j = 0; j < 32; ++j) h2[j] = fmaf(hk, wr[j], h2[j]);
    }

    float o0 = b3[0], o1 = b3[1];
    #pragma unroll
    for (int k = 0; k < 32; ++k) {
        float hk = fmaxf(h2[k], 0.0f);
        o0 = fmaf(hk, W3[2 * k + 0], o0);
        o1 = fmaf(hk, W3[2 * k + 1], o1);
    }
    *reinterpret_cast<float2*>(out + (size_t)2 * e) = make_float2(o0, o1);
}

// ---------------- launch ----------------
extern "C" void kernel_launch(void* const* d_in, const int* in_sizes, int n_in,
                              void* d_out, int out_size, void* d_ws, size_t ws_size,
                              hipStream_t stream) {
    const float* x    = (const float*)d_in[0];
    const int*   ei   = (const int*)d_in[1];
    const int*   src  = ei;
    const int*   dst  = ei + NE;
    const float* W1   = (const float*)d_in[2];
    const float* b1   = (const float*)d_in[3];
    const float* g1   = (const float*)d_in[4];
    const float* be1  = (const float*)d_in[5];
    const float* W2   = (const float*)d_in[6];
    const float* b2   = (const float*)d_in[7];
    const float* g2   = (const float*)d_in[8];
    const float* be2  = (const float*)d_in[9];
    const float* W3   = (const float*)d_in[10];
    const float* b3   = (const float*)d_in[11];
    const float* We1  = (const float*)d_in[12];
    const float* bme1 = (const float*)d_in[13];
    const float* We2  = (const float*)d_in[14];
    const float* bme2 = (const float*)d_in[15];
    const float* We3  = (const float*)d_in[16];
    const float* bme3 = (const float*)d_in[17];
    float* out = (float*)d_out;
    char* ws = (char*)d_ws;

    float* dsq      = (float*)ws;                         ws += NPAD * 4;
    float* dinv     = (float*)ws;                         ws += NPAD * 4;
    float* stats    = (float*)ws;                         ws += 1024 * 4;
    int*   cnt      = (int*)ws;                           ws += NPAD * 4;
    int*   cursor   = (int*)ws;                           ws += NPAD * 4;
    int*   bsum     = (int*)ws;                           ws += 256 * 4;
    int*   row_start= (int*)ws;                           ws += (NPAD + 16) * 4;
    int*   csr_src  = (int*)ws;                           ws += NE * 4;
    float* bufH     = (float*)ws;                         ws += (size_t)NN * 256 * 4;
    float* bufO     = (float*)ws;

    const int nblkE = (NE + 255) / 256;
    const int nblkNode = (NN + 3) / 4;

    // ---- CSR build + degree terms ----
    hipMemsetAsync(cnt, 0, NPAD * sizeof(int), stream);
    k_count_int<<<nblkE, 256, 0, stream>>>(dst, cnt);
    k_bsum<<<SCAN_BLOCKS, 256, 0, stream>>>(cnt, bsum);
    k_scan_bsum<<<1, 256, 0, stream>>>(bsum);
    k_scan_fin<<<SCAN_BLOCKS, 256, 0, stream>>>(cnt, bsum, row_start, cursor, dsq, dinv);
    k_fill<<<nblkE, 256, 0, stream>>>(src, dst, cursor, csr_src);

    // ---- layer 1: 256 -> 256 (128-tile gemm), agg, BN stats (apply fused into next gemm) ----
    {
        dim3 g(2, (NN + 127) / 128);
        k_gemm128<<<g, 256, 0, stream>>>(x, W1, bufH, NN, 256, 256);
    }
    k_agg256<<<nblkNode, 256, 0, stream>>>(bufH, row_start, csr_src, dsq, dinv, b1, bufO);
    hipMemsetAsync(stats, 0, 1024 * sizeof(float), stream);
    k_bn_stats<256><<<256, 256, 0, stream>>>(bufO, stats);
    k_bn_fin<<<1, 256, 0, stream>>>(stats, 256);

    // ---- layer 2: A = BN1(bufO) fused; 256 -> 64; agg; BN2 stats ----
    {
        dim3 g(1, (NN + 63) / 64);
        k_gemm<true><<<g, 256, 0, stream>>>(bufO, W2, bufH, NN, 256, 64, stats, g1, be1);
    }
    k_agg64<false><<<nblkNode, 256, 0, stream>>>(bufH, row_start, csr_src, dsq, dinv, b2, bufO);
    hipMemsetAsync(stats, 0, 1024 * sizeof(float), stream);
    k_bn_stats<64><<<256, 256, 0, stream>>>(bufO, stats);
    k_bn_fin<<<1, 256, 0, stream>>>(stats, 64);

    // ---- layer 3: A = BN2(bufO) fused; 64 -> 64; agg + relu ----
    {
        dim3 g(1, (NN + 63) / 64);
        k_gemm<true><<<g, 256, 0, stream>>>(bufO, W3, bufH, NN, 64, 64, stats, g2, be2);
    }
    k_agg64<true><<<nblkNode, 256, 0, stream>>>(bufH, row_start, csr_src, dsq, dinv, b3, bufO);

    // ---- layer 4: 64 -> 64 (same W3/b3, no relu) -> emb in bufO ----
    {
        dim3 g(1, (NN + 63) / 64);
        k_gemm<false><<<g, 256, 0, stream>>>(bufO, W3, bufH, NN, 64, 64, nullptr, nullptr, nullptr);
    }
    k_agg64<false><<<nblkNode, 256, 0, stream>>>(bufH, row_start, csr_src, dsq, dinv, b3, bufO);

    // ---- edge MLP, factored layer 1 ----
    float* Abuf = bufH;
    float* Bbuf = bufH + (size_t)NN * 64;
    {
        dim3 g(1, (NN + 63) / 64);
        k_gemm<false><<<g, 256, 0, stream>>>(bufO, We1, Abuf, NN, 64, 64, nullptr, nullptr, nullptr);
        k_gemm<false><<<g, 256, 0, stream>>>(bufO, We1 + (size_t)64 * 64, Bbuf, NN, 64, 64, nullptr, nullptr, nullptr);
    }
    k_edge_mlp3<<<(NE + EB - 1) / EB, EB, 0, stream>>>(Abuf, Bbuf, src, dst, bme1, We2, bme2, We3, bme3, out);

    (void)in_sizes; (void)n_in; (void)out_size; (void)ws_size;
}